// Round 1
// baseline (333.512 us; speedup 1.0000x reference)
//
#include <hip/hip_runtime.h>
#include <hip/hip_bf16.h>
#include <cstdint>
#include <cstddef>

// B=4, LQ=LK=1024, D=512, H=8. fp32 in/out; bf16 MFMA compute.
// R8: 256x256-tile / BK=32 / 8-wave phase-interleaved GEMM engine with
// quad-buffered LDS (128KB) and counted vmcnt(8) (never drains to 0 in
// steady state). Raw s_barrier + sched_barrier(0); setprio(1) around MFMA
// clusters. pvw split per-head -> 8 fp32 partials + reduce8.

typedef __bf16 bf16;
typedef __bf16 bf16x4 __attribute__((ext_vector_type(4)));
typedef __bf16 bf16x8 __attribute__((ext_vector_type(8)));
typedef float f32x4 __attribute__((ext_vector_type(4)));

__device__ inline void gload_lds16(const void* g, void* l) {
  __builtin_amdgcn_global_load_lds(
      (const __attribute__((address_space(1))) void*)g,
      (__attribute__((address_space(3))) void*)l, 16, 0, 0);
}

// C[256,256] tile at (m0,n0) of scale*(A . B^T). BK=32, 512 threads, 8 waves
// (2 M x 4 N), each wave owns a 128x64 sub-tile (8x4 16x16 fragments).
// LDS: 4 buffers x (A 8192 + B 8192 elems) = 128KB. Buffer c of tile t=c mod 4.
// Swizzle: 16B chunk q of row r lives at slot q ^ (r&3); applied on the global
// source side (global_load_lds writes linearly), undone on the ds_read side.
// Schedule per K-tile: 2 phases x {ds_read frags; stage next+3; s_barrier;
// setprio(1); 16 MFMA; setprio(0); s_barrier}, vmcnt(8) once per tile.
// Correctness: at tile t's closing vmcnt(8), allowed-outstanding = tiles
// t+2,t+3's 8 loads => tile t+1 landed before its reads. Staging of t+3 goes
// into buffer (t-1)&3, whose reads completed before the preceding barrier.
// MODE 0: C = acc*scale (bf16). MODE 1: P = mask? exp(acc*scale):0 (bf16) +
// atomic row sums. MODE 2: C = acc / sumrow[row] (fp32).
template <typename CT, int MODE>
__device__ __forceinline__ void gemm256(
    bf16* lds,
    const bf16* __restrict__ A, const bf16* __restrict__ B, CT* __restrict__ C,
    int K, int lda, int ldb, int ldc, int m0, int n0, float scale,
    const unsigned* __restrict__ mrow, float* __restrict__ sumrow)
{
  const int t = threadIdx.x;            // 0..511
  const int lane = t & 63;
  const int w = t >> 6;                 // 0..7
  const int wm = w >> 2, wn = w & 3;    // 2 x 4
  const int rr = lane & 15, q4 = lane >> 4;

  // Staging: thread t covers rows tr and tr+128, swizzled chunk tc.
  const int tr = t >> 2;                       // 0..127
  const int tc = (t & 3) ^ (tr & 3);           // pre-swizzled source chunk
  const bf16* Ag = A + (size_t)(m0 + tr) * lda + tc * 8;
  const bf16* Bg = B + (size_t)(n0 + tr) * ldb + tc * 8;
  bf16* ldsSt = lds + t * 8;  // linear dest: row tr, slot (t&3) == elem t*8

  const int nT = K >> 5;

  auto stageA = [&](int tt) {
    bf16* d = ldsSt + (tt & 3) * 16384;
    const bf16* s = Ag + tt * 32;
    gload_lds16(s, d);
    gload_lds16(s + (size_t)128 * lda, d + 4096);
  };
  auto stageB = [&](int tt) {
    bf16* d = ldsSt + (tt & 3) * 16384 + 8192;
    const bf16* s = Bg + tt * 32;
    gload_lds16(s, d);
    gload_lds16(s + (size_t)128 * ldb, d + 4096);
  };

  // Prologue: stage tiles 0,1,2 (12 loads); vmcnt(8) => tile 0 landed.
  stageA(0); stageB(0);
  stageA(1); stageB(1);
  stageA(2); stageB(2);
  asm volatile("s_waitcnt vmcnt(8)" ::: "memory");
  __builtin_amdgcn_s_barrier();
  __builtin_amdgcn_sched_barrier(0);

  f32x4 acc[8][4] = {};

  for (int tt = 0; tt < nT; ++tt) {
    const bf16* Al = lds + (tt & 3) * 16384;
    const bf16* Bl = Al + 8192;
    bf16x8 af[4], bg[4];

    // ---- phase A: frags A[m0..3] + B[n0..3]; MFMA m0..3 x n0..3 ----
#pragma unroll
    for (int m = 0; m < 4; ++m) {
      const int R = wm * 128 + m * 16 + rr;
      af[m] = *(const bf16x8*)(Al + R * 32 + ((q4 ^ (R & 3)) << 3));
    }
#pragma unroll
    for (int n = 0; n < 4; ++n) {
      const int R = wn * 64 + n * 16 + rr;
      bg[n] = *(const bf16x8*)(Bl + R * 32 + ((q4 ^ (R & 3)) << 3));
    }
    if (tt + 3 < nT) stageA(tt + 3);
    __builtin_amdgcn_s_barrier();
    __builtin_amdgcn_sched_barrier(0);
    __builtin_amdgcn_s_setprio(1);
#pragma unroll
    for (int m = 0; m < 4; ++m)
#pragma unroll
      for (int n = 0; n < 4; ++n)
        acc[m][n] = __builtin_amdgcn_mfma_f32_16x16x32_bf16(af[m], bg[n], acc[m][n], 0, 0, 0);
    __builtin_amdgcn_s_setprio(0);
    __builtin_amdgcn_s_barrier();
    __builtin_amdgcn_sched_barrier(0);

    // ---- phase B: frags A[m4..7] (B reused); MFMA m4..7 x n0..3 ----
#pragma unroll
    for (int m = 0; m < 4; ++m) {
      const int R = wm * 128 + 64 + m * 16 + rr;
      af[m] = *(const bf16x8*)(Al + R * 32 + ((q4 ^ (R & 3)) << 3));
    }
    if (tt + 3 < nT) stageB(tt + 3);
    __builtin_amdgcn_s_barrier();
    __builtin_amdgcn_sched_barrier(0);
    __builtin_amdgcn_s_setprio(1);
#pragma unroll
    for (int m = 0; m < 4; ++m)
#pragma unroll
      for (int n = 0; n < 4; ++n)
        acc[4 + m][n] = __builtin_amdgcn_mfma_f32_16x16x32_bf16(af[m], bg[n], acc[4 + m][n], 0, 0, 0);
    __builtin_amdgcn_s_setprio(0);

    // Counted wait: allow tiles t+2,t+3 in flight; certify t+1 landed.
    const int rem = nT - tt;
    if (rem > 3)       asm volatile("s_waitcnt vmcnt(8)" ::: "memory");
    else if (rem == 3) asm volatile("s_waitcnt vmcnt(4)" ::: "memory");
    else               asm volatile("s_waitcnt vmcnt(0)" ::: "memory");
    __builtin_amdgcn_s_barrier();
    __builtin_amdgcn_sched_barrier(0);
  }

  // C/D frag: col = lane&15, row = (lane>>4)*4 + reg  (same as proven R7 body)
  if (MODE == 0) {
#pragma unroll
    for (int m = 0; m < 8; ++m) {
#pragma unroll
      for (int n = 0; n < 4; ++n) {
        const int gr0 = m0 + wm * 128 + m * 16 + (q4 << 2);
        const int gc = n0 + wn * 64 + n * 16 + rr;
#pragma unroll
        for (int i = 0; i < 4; ++i)
          C[(size_t)(gr0 + i) * ldc + gc] = (CT)(acc[m][n][i] * scale);
      }
    }
  } else if (MODE == 1) {
    const int cb0 = (n0 + wn * 64) >> 5;
#pragma unroll
    for (int m = 0; m < 8; ++m) {
#pragma unroll
      for (int i = 0; i < 4; ++i) {
        const int row = m0 + wm * 128 + m * 16 + (q4 << 2) + i;
        const unsigned mw0 = mrow[(row << 5) + cb0];
        const unsigned mw1 = mrow[(row << 5) + cb0 + 1];
        float ps = 0.0f;
#pragma unroll
        for (int n = 0; n < 4; ++n) {
          const int gc = n0 + wn * 64 + n * 16 + rr;
          const unsigned mw = (n >= 2) ? mw1 : mw0;
          const unsigned bit = (mw >> (((n & 1) << 4) + rr)) & 1u;
          float p = bit ? __expf(acc[m][n][i] * scale) : 0.0f;
          C[(size_t)row * ldc + gc] = (CT)p;
          ps += p;
        }
        ps += __shfl_xor(ps, 1); ps += __shfl_xor(ps, 2);
        ps += __shfl_xor(ps, 4); ps += __shfl_xor(ps, 8);
        if (rr == 0) atomicAdd(sumrow + row, ps);
      }
    }
  } else {
#pragma unroll
    for (int m = 0; m < 8; ++m) {
      const int gr0 = m0 + wm * 128 + m * 16 + (q4 << 2);
      float inv[4];
#pragma unroll
      for (int i = 0; i < 4; ++i) inv[i] = 1.0f / sumrow[gr0 + i];
#pragma unroll
      for (int n = 0; n < 4; ++n) {
        const int gc = n0 + wn * 64 + n * 16 + rr;
#pragma unroll
        for (int i = 0; i < 4; ++i)
          C[(size_t)(gr0 + i) * ldc + gc] = (CT)(acc[m][n][i] * inv[i]);
      }
    }
  }
}

// ---- Dispatch 1: prep (cvt5 + cvtT + pack_mask + zero sums). grid 12832. ----
__global__ __launch_bounds__(256) void prep_kernel(
    const float* __restrict__ x, const float* __restrict__ st,
    const float* __restrict__ Wq, const float* __restrict__ Wk,
    const float* __restrict__ Wp, const float* __restrict__ Wv,
    const int* __restrict__ mask,
    bf16* __restrict__ xb, bf16* __restrict__ stb, bf16* __restrict__ wqb,
    bf16* __restrict__ wkb, bf16* __restrict__ wpb, bf16* __restrict__ WvT,
    unsigned* __restrict__ mbits, float* __restrict__ sums)
{
  const int lin = blockIdx.x;
  const int t = threadIdx.x;
  if (lin < 10240) {
    const float* s; bf16* d;
    switch (lin >> 11) {
      case 0: s = x; d = xb; break;
      case 1: s = st; d = stb; break;
      case 2: s = Wq; d = wqb; break;
      case 3: s = Wk; d = wkb; break;
      default: s = Wp; d = wpb; break;
    }
    const int i = ((lin & 2047) * 256 + t) * 4;
    float4 v = *(const float4*)(s + i);
    bf16x4 o;
    o[0] = (bf16)v.x; o[1] = (bf16)v.y; o[2] = (bf16)v.z; o[3] = (bf16)v.w;
    *(bf16x4*)(d + i) = o;
  } else if (lin < 12288) {
    // WvT[h][d][e'] = Wv[h][e'][d]
    const int gid = (lin - 10240) * 256 + t;      // [0, 524288)
    const int e0 = (gid & 127) * 4;
    const int d = (gid >> 7) & 511;
    const int h = gid >> 16;
    const float* src = Wv + (size_t)h * 262144 + (size_t)e0 * 512 + d;
    bf16x4 o;
    o[0] = (bf16)src[0];
    o[1] = (bf16)src[512];
    o[2] = (bf16)src[1024];
    o[3] = (bf16)src[1536];
    *(bf16x4*)(WvT + (size_t)h * 262144 + (size_t)d * 512 + e0) = o;
  } else if (lin < 12800) {
    const int gid = (lin - 12288) * 256 + t;      // [0, 131072)
    const int* src = mask + (size_t)gid * 32;
    unsigned bits = 0;
#pragma unroll
    for (int j = 0; j < 32; j += 4) {
      int4 v = *(const int4*)(src + j);
      if (v.x) bits |= 1u << j;
      if (v.y) bits |= 1u << (j + 1);
      if (v.z) bits |= 1u << (j + 2);
      if (v.w) bits |= 1u << (j + 3);
    }
    mbits[gid] = bits;
  } else {
    const int i = ((lin - 12800) * 256 + t) * 4;  // [0, 32768) floats
    *(float4*)(sums + i) = make_float4(0.f, 0.f, 0.f, 0.f);
  }
}

// ---- Dispatch 2: proj (q/k projections + U = Wp_h.Wv_h). grid 544x512. ----
__global__ __launch_bounds__(512, 2) void proj_kernel(
    const bf16* __restrict__ xb, const bf16* __restrict__ stb,
    const bf16* __restrict__ wqb, const bf16* __restrict__ wkb,
    const bf16* __restrict__ wpb, const bf16* __restrict__ WvT,
    bf16* __restrict__ q, bf16* __restrict__ k, bf16* __restrict__ U)
{
  __shared__ bf16 lds[65536];   // 128 KB
  const int bid = blockIdx.x;
  const int g = (bid & 7) * 68 + (bid >> 3);   // XCD-chunked, 544 = 8*68
  if (g < 512) {
    const int z = g >> 3;        // 0..63 : job*32 + (zb*8+zh)
    const int tile = g & 7;      // 4 m x 2 n
    const int job = z >> 5;
    const int zz = z & 31;
    const size_t zb = zz >> 3, zh = zz & 7;
    const bf16* Ain = job ? stb : xb;
    const bf16* W = job ? wkb : wqb;
    bf16* Cout = job ? k : q;
    gemm256<bf16, 0>(lds, Ain + zb * 524288, W + zh * 262144,
        Cout + zb * 4194304 + zh * 524288, 512, 512, 512, 512,
        (tile >> 1) * 256, (tile & 1) * 256, 1.0f, nullptr, nullptr);
  } else {
    // U_h[e,d] = sum_e' Wp[e, h*512+e'] * WvT_h[d, e']
    const int g2 = g - 512;      // 0..31
    const int h = g2 >> 2;
    const int tile = g2 & 3;     // 2 m x 2 n
    gemm256<bf16, 0>(lds, wpb + (size_t)h * 512, WvT + (size_t)h * 262144,
        U + (size_t)h * 262144, 512, 4096, 512, 512,
        (tile >> 1) * 256, (tile & 1) * 256, 1.0f, nullptr, nullptr);
  }
}

// ---- Dispatch 3: big (scores+exp+rowsum, and VWT = U.states^T). grid 768x512. ----
__global__ __launch_bounds__(512, 2) void big_kernel(
    const bf16* __restrict__ q, const bf16* __restrict__ k,
    const bf16* __restrict__ U, const bf16* __restrict__ stb,
    bf16* __restrict__ P, bf16* __restrict__ VWT,
    const unsigned* __restrict__ mbits, float* __restrict__ sums, float scale)
{
  __shared__ bf16 lds[65536];
  const int bid = blockIdx.x;
  const int g = (bid & 7) * 96 + (bid >> 3);   // 768 = 8*96
  if (g < 512) {
    // scores: z in [0,32), 16 tiles (4m x 4n)
    const int z = g >> 4;
    const int tile = g & 15;
    const size_t zb = z >> 3, zh = z & 7;
    gemm256<bf16, 1>(lds,
        q + zb * 4194304 + zh * 524288,
        k + zb * 4194304 + zh * 524288,
        P + zb * 8388608 + zh * 1048576,
        512, 512, 512, 1024,
        (tile >> 2) * 256, (tile & 3) * 256, scale,
        mbits + (zb << 15), sums + ((size_t)z << 10));
  } else {
    // VWT[b,h][e,s] = U_h . states_b^T : z in [0,32), 8 tiles (2m x 4n)
    const int g2 = g - 512;
    const int z = g2 >> 3;
    const int tile = g2 & 7;
    const size_t zb = z >> 3, zh = z & 7;
    gemm256<bf16, 0>(lds, U + zh * 262144, stb + zb * 524288,
        VWT + zb * 4194304 + zh * 524288, 512, 512, 512, 1024,
        (tile >> 2) * 256, (tile & 3) * 256, 1.0f, nullptr, nullptr);
  }
}

// ---- Dispatch 4: pvw — part[h] = (1/sum_h) ⊙ (P_h·VWT_h^T). grid 256x512. ----
__global__ __launch_bounds__(512, 2) void pvw_kernel(
    const bf16* __restrict__ P, const bf16* __restrict__ VWT,
    float* __restrict__ sums, float* __restrict__ part)
{
  __shared__ bf16 lds[65536];
  const int bid = blockIdx.x;
  const int g = (bid & 7) * 32 + (bid >> 3);   // 256 = 8*32
  const int z = g >> 3;        // 0..31 = (b,h)
  const int tile = g & 7;      // 4 m(l) x 2 n(e)
  const size_t zb = z >> 3, zh = z & 7;
  gemm256<float, 2>(lds,
      P + zb * 8388608 + zh * 1048576,
      VWT + zb * 4194304 + zh * 524288,
      part + zh * 2097152 + zb * 524288,
      1024, 1024, 1024, 512,
      (tile >> 1) * 256, (tile & 1) * 256, 1.0f,
      nullptr, sums + ((size_t)z << 10));
}

// ---- Dispatch 5: out = sum of 8 per-head parts. grid 2048x256. ----
__global__ __launch_bounds__(256) void reduce8(
    const float* __restrict__ part, float* __restrict__ out)
{
  const size_t i = ((size_t)blockIdx.x * 256 + threadIdx.x) * 4;
  float4 o = *(const float4*)(part + i);
#pragma unroll
  for (int h = 1; h < 8; ++h) {
    float4 a = *(const float4*)(part + (size_t)h * 2097152 + i);
    o.x += a.x; o.y += a.y; o.z += a.z; o.w += a.w;
  }
  *(float4*)(out + i) = o;
}

extern "C" void kernel_launch(void* const* d_in, const int* in_sizes, int n_in,
                              void* d_out, int out_size, void* d_ws, size_t ws_size,
                              hipStream_t stream) {
  const float* x    = (const float*)d_in[0];
  const float* st   = (const float*)d_in[1];
  const int*   mask = (const int*)d_in[2];
  const float* Wq   = (const float*)d_in[3];
  const float* Wk   = (const float*)d_in[4];
  const float* Wv   = (const float*)d_in[5];
  const float* Wp   = (const float*)d_in[6];
  float* out = (float*)d_out;

  char* ws = (char*)d_ws;
  const size_t MB = 1048576;
  bf16* xb  = (bf16*)(ws);               // 4MB
  bf16* stb = (bf16*)(ws + 4 * MB);      // 4MB (live through VWT)
  bf16* wqb = (bf16*)(ws + 8 * MB);      // 4MB
  bf16* wkb = (bf16*)(ws + 12 * MB);     // 4MB
  bf16* wpb = (bf16*)(ws + 16 * MB);     // 4MB
  bf16* WvT = (bf16*)(ws + 20 * MB);     // 4MB [8,512,512] transposed
  bf16* U   = (bf16*)(ws + 24 * MB);     // 4MB [8,512,512] Wp_h.Wv_h
  bf16* q   = (bf16*)(ws + 28 * MB);     // 32MB; dead after scores
  bf16* k   = (bf16*)(ws + 60 * MB);     // 32MB; dead after scores
  bf16* VWT = (bf16*)(ws + 92 * MB);     // 32MB [4,8,512,1024]
  bf16* sc  = (bf16*)(ws + 124 * MB);    // 64MB P = exp(scores)
  unsigned* mbits = (unsigned*)(ws + 188 * MB);  // 512KB
  float*    sums  = (float*)(ws + 189 * MB);     // 128KB
  float*    part  = (float*)(ws + 28 * MB);      // 64MB fp32 (over q+k)

  const float scale = 0.04419417382415922f;  // 1/sqrt(512)

  prep_kernel<<<dim3(12832), dim3(256), 0, stream>>>(x, st, Wq, Wk, Wp, Wv, mask,
      xb, stb, wqb, wkb, wpb, WvT, mbits, sums);

  proj_kernel<<<dim3(544), dim3(512), 0, stream>>>(xb, stb, wqb, wkb, wpb, WvT,
      q, k, U);

  big_kernel<<<dim3(768), dim3(512), 0, stream>>>(q, k, U, stb, sc, VWT,
      mbits, sums, scale);

  pvw_kernel<<<dim3(256), dim3(512), 0, stream>>>(sc, VWT, sums, part);

  reduce8<<<dim3(2048), dim3(256), 0, stream>>>(part, out);
}

// Round 3
// 315.865 us; speedup vs baseline: 1.0559x; 1.0559x over previous
//
#include <hip/hip_runtime.h>
#include <hip/hip_bf16.h>
#include <cstdint>
#include <cstddef>

// B=4, LQ=LK=1024, D=512, H=8. fp32 in/out; bf16 MFMA compute.
// R9b: resubmit of R9 (round-2 bench died in infra; no counters).
// 256x256 tile, BK=64 (proven conflict-free [256][64] layout with
// slot = chunk ^ (row&7)), 2 LDS buffers (128KB), 4 phases/tile with
// dependency-chained staging (S1..S4) and counted vmcnt(4) (never 0 in
// steady state). 16 MFMA per barrier, setprio(1) around MFMA clusters.

typedef __bf16 bf16;
typedef __bf16 bf16x4 __attribute__((ext_vector_type(4)));
typedef __bf16 bf16x8 __attribute__((ext_vector_type(8)));
typedef float f32x4 __attribute__((ext_vector_type(4)));

__device__ inline void gload_lds16(const void* g, void* l) {
  __builtin_amdgcn_global_load_lds(
      (const __attribute__((address_space(1))) void*)g,
      (__attribute__((address_space(3))) void*)l, 16, 0, 0);
}

#define SBAR0 __builtin_amdgcn_sched_barrier(0)

// C[256,256] tile at (m0,n0) of scale*(A . B^T). 512 thr, 8 waves (2M x 4N),
// per-wave 128x64 output (8x4 16x16 frags). LDS: 2 buf x (A[256][64] +
// B[256][64]) bf16 = 128KB. Swizzle: 16B chunk c of row r at slot c^(r&7).
// Stage order per tile (of tile t+1, into buf (t+1)&1):
//   S1 = A rows {0-63,128-191}   (P1-A data)     staged in P1
//   S2 = B rows {0-31,64-95,128-159,192-223} (P1-B) staged in P2
//   S3 = B rows {32-63,96-127,160-191,224-255} (P2-B) staged in P3
//   S4 = A rows {64-127,192-255} (P3-A)          staged in P4
// Phase deps (tile t): P1<-S1,S2 ; P2<-S3 ; P3<-S4 ; P4<-nothing.
// vmcnt(4) after P1-stage (drains S3(t)), after P2-stage (drains S4(t)),
// after P4-stage (drains S1,S2(t+1)). Steady state >=4 loads in flight.
// MODE 0: C = acc*scale (bf16). MODE 1: P = mask? exp(acc*scale):0 (bf16) +
// atomic row sums. MODE 2: C = acc / sumrow[row] (fp32).
template <typename CT, int MODE>
__device__ __forceinline__ void gemm256(
    bf16* lds,
    const bf16* __restrict__ A, const bf16* __restrict__ B, CT* __restrict__ C,
    int K, int lda, int ldb, int ldc, int m0, int n0, float scale,
    const unsigned* __restrict__ mrow, float* __restrict__ sumrow)
{
  const int t = threadIdx.x;            // 0..511
  const int lane = t & 63;
  const int w = t >> 6;                 // 0..7
  const int wm = w >> 2, wn = w & 3;    // 2 x 4
  const int rr = lane & 15, q4 = lane >> 4;

  // Staging thread coords (R7-proven pattern, extended to 512 threads).
  const int s64row = t >> 3;                 // 0..63
  const int ssl    = t & 7;                  // dest slot
  const int s64ch  = ssl ^ (s64row & 7);     // source chunk (64-row stage)
  const int tb     = t & 255;
  const int sbrow  = tb >> 3;                // 0..31
  const int sbch   = ssl ^ (sbrow & 7);      // source chunk (32-row bands)
  const int hb     = t >> 8;                 // which band within a B stage

  const int nT = K >> 6;

  // Stage 64 consecutive A rows [row0,row0+64) of k-tile tt.
  auto stageA = [&](int tt, int row0) {
    const int r = row0 + s64row;
    gload_lds16(A + (size_t)(m0 + r) * lda + tt * 64 + s64ch * 8,
                lds + (tt & 1) * 32768 + row0 * 64 + t * 8);
  };
  // Stage B bands [b0,b0+32) and [b0+64,b0+96) of k-tile tt.
  auto stageB = [&](int tt, int b0) {
    const int r = b0 + hb * 64 + sbrow;
    gload_lds16(B + (size_t)(n0 + r) * ldb + tt * 64 + sbch * 8,
                lds + (tt & 1) * 32768 + 16384 + r * 64 + ssl * 8);
  };

  // Prologue: full tile 0 in stage order S1,S2,S3,S4; certify S1,S2.
  stageA(0, 0);   stageA(0, 128);   // S1
  stageB(0, 0);   stageB(0, 128);   // S2
  stageB(0, 32);  stageB(0, 160);   // S3
  stageA(0, 64);  stageA(0, 192);   // S4
  SBAR0;
  asm volatile("s_waitcnt vmcnt(4)" ::: "memory");
  __builtin_amdgcn_s_barrier();
  SBAR0;

  f32x4 acc[8][4] = {};
  bf16x8 af[2][4];   // [kk][m within half]
  bf16x8 bgf[2][4];  // [kk][n], lives across the whole tile

  // Fragment swizzle collapses: R&7 == rr&7 for every fragment row.
  const int sw0 = (q4 ^ (rr & 7)) << 3;  // elem offset, kk=0
  const int sw1 = sw0 ^ 32;              // kk=1

  for (int tt = 0; tt < nT; ++tt) {
    const bf16* Ab = lds + (tt & 1) * 32768 + (wm * 128 + rr) * 64;
    const bf16* Bb = lds + (tt & 1) * 32768 + 16384 + (wn * 64 + rr) * 64;
    const bool pf = (tt + 1) < nT;

    // ---------------- P1: A m0-3, B n0-1; MFMA m0-3 x n0-1 ----------------
#pragma unroll
    for (int m = 0; m < 4; ++m) {
      af[0][m] = *(const bf16x8*)(Ab + m * 1024 + sw0);
      af[1][m] = *(const bf16x8*)(Ab + m * 1024 + sw1);
    }
#pragma unroll
    for (int n = 0; n < 2; ++n) {
      bgf[0][n] = *(const bf16x8*)(Bb + n * 1024 + sw0);
      bgf[1][n] = *(const bf16x8*)(Bb + n * 1024 + sw1);
    }
    if (pf) { stageA(tt + 1, 0); stageA(tt + 1, 128); }   // S1'
    SBAR0;
    if (pf) asm volatile("s_waitcnt vmcnt(4)" ::: "memory");
    else    asm volatile("s_waitcnt vmcnt(2)" ::: "memory");
    __builtin_amdgcn_s_barrier();
    SBAR0;
    __builtin_amdgcn_s_setprio(1);
#pragma unroll
    for (int kk = 0; kk < 2; ++kk)
#pragma unroll
      for (int m = 0; m < 4; ++m)
#pragma unroll
        for (int n = 0; n < 2; ++n)
          acc[m][n] = __builtin_amdgcn_mfma_f32_16x16x32_bf16(af[kk][m], bgf[kk][n], acc[m][n], 0, 0, 0);
    __builtin_amdgcn_s_setprio(0);

    // ---------------- P2: B n2-3; MFMA m0-3 x n2-3 ----------------
#pragma unroll
    for (int n = 2; n < 4; ++n) {
      bgf[0][n] = *(const bf16x8*)(Bb + n * 1024 + sw0);
      bgf[1][n] = *(const bf16x8*)(Bb + n * 1024 + sw1);
    }
    if (pf) { stageB(tt + 1, 0); stageB(tt + 1, 128); }   // S2'
    SBAR0;
    if (pf) asm volatile("s_waitcnt vmcnt(4)" ::: "memory");
    else    asm volatile("s_waitcnt vmcnt(0)" ::: "memory");
    __builtin_amdgcn_s_barrier();
    SBAR0;
    __builtin_amdgcn_s_setprio(1);
#pragma unroll
    for (int kk = 0; kk < 2; ++kk)
#pragma unroll
      for (int m = 0; m < 4; ++m)
#pragma unroll
        for (int n = 2; n < 4; ++n)
          acc[m][n] = __builtin_amdgcn_mfma_f32_16x16x32_bf16(af[kk][m], bgf[kk][n], acc[m][n], 0, 0, 0);
    __builtin_amdgcn_s_setprio(0);

    // ---------------- P3: A m4-7; MFMA m4-7 x n0-1 ----------------
#pragma unroll
    for (int m = 0; m < 4; ++m) {
      af[0][m] = *(const bf16x8*)(Ab + (64 + m * 16) * 64 + sw0);
      af[1][m] = *(const bf16x8*)(Ab + (64 + m * 16) * 64 + sw1);
    }
    if (pf) { stageB(tt + 1, 32); stageB(tt + 1, 160); }  // S3'
    SBAR0;
    __builtin_amdgcn_s_barrier();   // no vmcnt: P4 reads nothing new
    SBAR0;
    __builtin_amdgcn_s_setprio(1);
#pragma unroll
    for (int kk = 0; kk < 2; ++kk)
#pragma unroll
      for (int m = 0; m < 4; ++m)
#pragma unroll
        for (int n = 0; n < 2; ++n)
          acc[4 + m][n] = __builtin_amdgcn_mfma_f32_16x16x32_bf16(af[kk][m], bgf[kk][n], acc[4 + m][n], 0, 0, 0);
    __builtin_amdgcn_s_setprio(0);

    // ---------------- P4: MFMA m4-7 x n2-3 ----------------
    if (pf) { stageA(tt + 1, 64); stageA(tt + 1, 192); }  // S4'
    SBAR0;
    if (pf) asm volatile("s_waitcnt vmcnt(4)" ::: "memory");
    __builtin_amdgcn_s_barrier();
    SBAR0;
    __builtin_amdgcn_s_setprio(1);
#pragma unroll
    for (int kk = 0; kk < 2; ++kk)
#pragma unroll
      for (int m = 0; m < 4; ++m)
#pragma unroll
        for (int n = 2; n < 4; ++n)
          acc[4 + m][n] = __builtin_amdgcn_mfma_f32_16x16x32_bf16(af[kk][m], bgf[kk][n], acc[4 + m][n], 0, 0, 0);
    __builtin_amdgcn_s_setprio(0);
  }

  // C/D frag: col = lane&15, row = (lane>>4)*4 + reg  (R7/R8-verified)
  if (MODE == 0) {
#pragma unroll
    for (int m = 0; m < 8; ++m) {
#pragma unroll
      for (int n = 0; n < 4; ++n) {
        const int gr0 = m0 + wm * 128 + m * 16 + (q4 << 2);
        const int gc = n0 + wn * 64 + n * 16 + rr;
#pragma unroll
        for (int i = 0; i < 4; ++i)
          C[(size_t)(gr0 + i) * ldc + gc] = (CT)(acc[m][n][i] * scale);
      }
    }
  } else if (MODE == 1) {
    const int cb0 = (n0 + wn * 64) >> 5;
#pragma unroll
    for (int m = 0; m < 8; ++m) {
#pragma unroll
      for (int i = 0; i < 4; ++i) {
        const int row = m0 + wm * 128 + m * 16 + (q4 << 2) + i;
        const unsigned mw0 = mrow[(row << 5) + cb0];
        const unsigned mw1 = mrow[(row << 5) + cb0 + 1];
        float ps = 0.0f;
#pragma unroll
        for (int n = 0; n < 4; ++n) {
          const int gc = n0 + wn * 64 + n * 16 + rr;
          const unsigned mw = (n >= 2) ? mw1 : mw0;
          const unsigned bit = (mw >> (((n & 1) << 4) + rr)) & 1u;
          float p = bit ? __expf(acc[m][n][i] * scale) : 0.0f;
          C[(size_t)row * ldc + gc] = (CT)p;
          ps += p;
        }
        ps += __shfl_xor(ps, 1); ps += __shfl_xor(ps, 2);
        ps += __shfl_xor(ps, 4); ps += __shfl_xor(ps, 8);
        if (rr == 0) atomicAdd(sumrow + row, ps);
      }
    }
  } else {
#pragma unroll
    for (int m = 0; m < 8; ++m) {
      const int gr0 = m0 + wm * 128 + m * 16 + (q4 << 2);
      float inv[4];
#pragma unroll
      for (int i = 0; i < 4; ++i) inv[i] = 1.0f / sumrow[gr0 + i];
#pragma unroll
      for (int n = 0; n < 4; ++n) {
        const int gc = n0 + wn * 64 + n * 16 + rr;
#pragma unroll
        for (int i = 0; i < 4; ++i)
          C[(size_t)(gr0 + i) * ldc + gc] = (CT)(acc[m][n][i] * inv[i]);
      }
    }
  }
}

// ---- Dispatch 1: prep (cvt5 + cvtT + pack_mask + zero sums). grid 12832. ----
__global__ __launch_bounds__(256) void prep_kernel(
    const float* __restrict__ x, const float* __restrict__ st,
    const float* __restrict__ Wq, const float* __restrict__ Wk,
    const float* __restrict__ Wp, const float* __restrict__ Wv,
    const int* __restrict__ mask,
    bf16* __restrict__ xb, bf16* __restrict__ stb, bf16* __restrict__ wqb,
    bf16* __restrict__ wkb, bf16* __restrict__ wpb, bf16* __restrict__ WvT,
    unsigned* __restrict__ mbits, float* __restrict__ sums)
{
  const int lin = blockIdx.x;
  const int t = threadIdx.x;
  if (lin < 10240) {
    const float* s; bf16* d;
    switch (lin >> 11) {
      case 0: s = x; d = xb; break;
      case 1: s = st; d = stb; break;
      case 2: s = Wq; d = wqb; break;
      case 3: s = Wk; d = wkb; break;
      default: s = Wp; d = wpb; break;
    }
    const int i = ((lin & 2047) * 256 + t) * 4;
    float4 v = *(const float4*)(s + i);
    bf16x4 o;
    o[0] = (bf16)v.x; o[1] = (bf16)v.y; o[2] = (bf16)v.z; o[3] = (bf16)v.w;
    *(bf16x4*)(d + i) = o;
  } else if (lin < 12288) {
    // WvT[h][d][e'] = Wv[h][e'][d]
    const int gid = (lin - 10240) * 256 + t;      // [0, 524288)
    const int e0 = (gid & 127) * 4;
    const int d = (gid >> 7) & 511;
    const int h = gid >> 16;
    const float* src = Wv + (size_t)h * 262144 + (size_t)e0 * 512 + d;
    bf16x4 o;
    o[0] = (bf16)src[0];
    o[1] = (bf16)src[512];
    o[2] = (bf16)src[1024];
    o[3] = (bf16)src[1536];
    *(bf16x4*)(WvT + (size_t)h * 262144 + (size_t)d * 512 + e0) = o;
  } else if (lin < 12800) {
    const int gid = (lin - 12288) * 256 + t;      // [0, 131072)
    const int* src = mask + (size_t)gid * 32;
    unsigned bits = 0;
#pragma unroll
    for (int j = 0; j < 32; j += 4) {
      int4 v = *(const int4*)(src + j);
      if (v.x) bits |= 1u << j;
      if (v.y) bits |= 1u << (j + 1);
      if (v.z) bits |= 1u << (j + 2);
      if (v.w) bits |= 1u << (j + 3);
    }
    mbits[gid] = bits;
  } else {
    const int i = ((lin - 12800) * 256 + t) * 4;  // [0, 32768) floats
    *(float4*)(sums + i) = make_float4(0.f, 0.f, 0.f, 0.f);
  }
}

// ---- Dispatch 2: proj (q/k projections + U = Wp_h.Wv_h). grid 544x512. ----
__global__ __launch_bounds__(512, 2) void proj_kernel(
    const bf16* __restrict__ xb, const bf16* __restrict__ stb,
    const bf16* __restrict__ wqb, const bf16* __restrict__ wkb,
    const bf16* __restrict__ wpb, const bf16* __restrict__ WvT,
    bf16* __restrict__ q, bf16* __restrict__ k, bf16* __restrict__ U)
{
  __shared__ bf16 lds[65536];   // 128 KB
  const int bid = blockIdx.x;
  const int g = (bid & 7) * 68 + (bid >> 3);   // XCD-chunked, 544 = 8*68
  if (g < 512) {
    const int z = g >> 3;        // 0..63 : job*32 + (zb*8+zh)
    const int tile = g & 7;      // 4 m x 2 n
    const int job = z >> 5;
    const int zz = z & 31;
    const size_t zb = zz >> 3, zh = zz & 7;
    const bf16* Ain = job ? stb : xb;
    const bf16* W = job ? wkb : wqb;
    bf16* Cout = job ? k : q;
    gemm256<bf16, 0>(lds, Ain + zb * 524288, W + zh * 262144,
        Cout + zb * 4194304 + zh * 524288, 512, 512, 512, 512,
        (tile >> 1) * 256, (tile & 1) * 256, 1.0f, nullptr, nullptr);
  } else {
    // U_h[e,d] = sum_e' Wp[e, h*512+e'] * WvT_h[d, e']
    const int g2 = g - 512;      // 0..31
    const int h = g2 >> 2;
    const int tile = g2 & 3;     // 2 m x 2 n
    gemm256<bf16, 0>(lds, wpb + (size_t)h * 512, WvT + (size_t)h * 262144,
        U + (size_t)h * 262144, 512, 4096, 512, 512,
        (tile >> 1) * 256, (tile & 1) * 256, 1.0f, nullptr, nullptr);
  }
}

// ---- Dispatch 3: big (scores+exp+rowsum, and VWT = U.states^T). grid 768x512. ----
__global__ __launch_bounds__(512, 2) void big_kernel(
    const bf16* __restrict__ q, const bf16* __restrict__ k,
    const bf16* __restrict__ U, const bf16* __restrict__ stb,
    bf16* __restrict__ P, bf16* __restrict__ VWT,
    const unsigned* __restrict__ mbits, float* __restrict__ sums, float scale)
{
  __shared__ bf16 lds[65536];
  const int bid = blockIdx.x;
  const int g = (bid & 7) * 96 + (bid >> 3);   // 768 = 8*96
  if (g < 512) {
    // scores: z in [0,32), 16 tiles (4m x 4n)
    const int z = g >> 4;
    const int tile = g & 15;
    const size_t zb = z >> 3, zh = z & 7;
    gemm256<bf16, 1>(lds,
        q + zb * 4194304 + zh * 524288,
        k + zb * 4194304 + zh * 524288,
        P + zb * 8388608 + zh * 1048576,
        512, 512, 512, 1024,
        (tile >> 2) * 256, (tile & 3) * 256, scale,
        mbits + (zb << 15), sums + ((size_t)z << 10));
  } else {
    // VWT[b,h][e,s] = U_h . states_b^T : z in [0,32), 8 tiles (2m x 4n)
    const int g2 = g - 512;
    const int z = g2 >> 3;
    const int tile = g2 & 7;
    const size_t zb = z >> 3, zh = z & 7;
    gemm256<bf16, 0>(lds, U + zh * 262144, stb + zb * 524288,
        VWT + zb * 4194304 + zh * 524288, 512, 512, 512, 1024,
        (tile >> 2) * 256, (tile & 3) * 256, 1.0f, nullptr, nullptr);
  }
}

// ---- Dispatch 4: pvw — part[h] = (1/sum_h) ⊙ (P_h·VWT_h^T). grid 256x512. ----
__global__ __launch_bounds__(512, 2) void pvw_kernel(
    const bf16* __restrict__ P, const bf16* __restrict__ VWT,
    float* __restrict__ sums, float* __restrict__ part)
{
  __shared__ bf16 lds[65536];
  const int bid = blockIdx.x;
  const int g = (bid & 7) * 32 + (bid >> 3);   // 256 = 8*32
  const int z = g >> 3;        // 0..31 = (b,h)
  const int tile = g & 7;      // 4 m(l) x 2 n(e)
  const size_t zb = z >> 3, zh = z & 7;
  gemm256<float, 2>(lds,
      P + zb * 8388608 + zh * 1048576,
      VWT + zb * 4194304 + zh * 524288,
      part + zh * 2097152 + zb * 524288,
      1024, 1024, 1024, 512,
      (tile >> 1) * 256, (tile & 1) * 256, 1.0f,
      nullptr, sums + ((size_t)z << 10));
}

// ---- Dispatch 5: out = sum of 8 per-head parts. grid 2048x256. ----
__global__ __launch_bounds__(256) void reduce8(
    const float* __restrict__ part, float* __restrict__ out)
{
  const size_t i = ((size_t)blockIdx.x * 256 + threadIdx.x) * 4;
  float4 o = *(const float4*)(part + i);
#pragma unroll
  for (int h = 1; h < 8; ++h) {
    float4 a = *(const float4*)(part + (size_t)h * 2097152 + i);
    o.x += a.x; o.y += a.y; o.z += a.z; o.w += a.w;
  }
  *(float4*)(out + i) = o;
}

extern "C" void kernel_launch(void* const* d_in, const int* in_sizes, int n_in,
                              void* d_out, int out_size, void* d_ws, size_t ws_size,
                              hipStream_t stream) {
  const float* x    = (const float*)d_in[0];
  const float* st   = (const float*)d_in[1];
  const int*   mask = (const int*)d_in[2];
  const float* Wq   = (const float*)d_in[3];
  const float* Wk   = (const float*)d_in[4];
  const float* Wv   = (const float*)d_in[5];
  const float* Wp   = (const float*)d_in[6];
  float* out = (float*)d_out;

  char* ws = (char*)d_ws;
  const size_t MB = 1048576;
  bf16* xb  = (bf16*)(ws);               // 4MB
  bf16* stb = (bf16*)(ws + 4 * MB);      // 4MB (live through VWT)
  bf16* wqb = (bf16*)(ws + 8 * MB);      // 4MB
  bf16* wkb = (bf16*)(ws + 12 * MB);     // 4MB
  bf16* wpb = (bf16*)(ws + 16 * MB);     // 4MB
  bf16* WvT = (bf16*)(ws + 20 * MB);     // 4MB [8,512,512] transposed
  bf16* U   = (bf16*)(ws + 24 * MB);     // 4MB [8,512,512] Wp_h.Wv_h
  bf16* q   = (bf16*)(ws + 28 * MB);     // 32MB; dead after scores
  bf16* k   = (bf16*)(ws + 60 * MB);     // 32MB; dead after scores
  bf16* VWT = (bf16*)(ws + 92 * MB);     // 32MB [4,8,512,1024]
  bf16* sc  = (bf16*)(ws + 124 * MB);    // 64MB P = exp(scores)
  unsigned* mbits = (unsigned*)(ws + 188 * MB);  // 512KB
  float*    sums  = (float*)(ws + 189 * MB);     // 128KB
  float*    part  = (float*)(ws + 28 * MB);      // 64MB fp32 (over q+k)

  const float scale = 0.04419417382415922f;  // 1/sqrt(512)

  prep_kernel<<<dim3(12832), dim3(256), 0, stream>>>(x, st, Wq, Wk, Wp, Wv, mask,
      xb, stb, wqb, wkb, wpb, WvT, mbits, sums);

  proj_kernel<<<dim3(544), dim3(512), 0, stream>>>(xb, stb, wqb, wkb, wpb, WvT,
      q, k, U);

  big_kernel<<<dim3(768), dim3(512), 0, stream>>>(q, k, U, stb, sc, VWT,
      mbits, sums, scale);

  pvw_kernel<<<dim3(256), dim3(512), 0, stream>>>(sc, VWT, sums, part);

  reduce8<<<dim3(2048), dim3(256), 0, stream>>>(part, out);
}

// Round 4
// 304.758 us; speedup vs baseline: 1.0944x; 1.0364x over previous
//
#include <hip/hip_runtime.h>
#include <hip/hip_bf16.h>
#include <cstdint>
#include <cstddef>

// B=4, LQ=LK=1024, D=512, H=8. fp32 in/out; bf16 MFMA compute.
// R10: R9 schedule (256x256 tile, BK=64 conflict-free layout, S1..S4
// dependency-chained staging, counted vmcnt(4)) with the pinning removed:
// - sched_barrier(0) ONLY after each vmcnt+s_barrier pair
// - K is a template param; K-loop fully unrolled -> all buffer selects,
//   pf-branches and address offsets are compile-time constants
// - hoisted per-thread stage base pointers (no per-phase address recompute)

typedef __bf16 bf16;
typedef __bf16 bf16x4 __attribute__((ext_vector_type(4)));
typedef __bf16 bf16x8 __attribute__((ext_vector_type(8)));
typedef float f32x4 __attribute__((ext_vector_type(4)));

__device__ inline void gload_lds16(const void* g, void* l) {
  __builtin_amdgcn_global_load_lds(
      (const __attribute__((address_space(1))) void*)g,
      (__attribute__((address_space(3))) void*)l, 16, 0, 0);
}

#define SBAR0 __builtin_amdgcn_sched_barrier(0)

// C[256,256] tile at (m0,n0) of scale*(A . B^T). 512 thr, 8 waves (2M x 4N),
// per-wave 128x64 output (8x4 16x16 frags). LDS: 2 buf x (A[256][64] +
// B[256][64]) bf16 = 128KB. Swizzle: 16B chunk c of row r at slot c^(r&7).
// Stage groups for tile t+1 (into buf (t+1)&1), issued during tile t:
//   S1 (in P1) = A rows {0-63,128-191}
//   S2 (in P2) = B rows {0-31,64-95,128-159,192-223}
//   S3 (in P3) = B rows {32-63,96-127,160-191,224-255}
//   S4 (in P4) = A rows {64-127,192-255}
// Phase deps (tile t): P1<-S1,S2 ; P2<-S3 ; P3<-S4 ; P4<-none.
// vmcnt(4) after P1-stage (drains S3(t)), after P2-stage (drains S4(t)),
// after P4-stage (drains S1,S2(t+1)). Steady state >=4 loads in flight.
// MODE 0: C = acc*scale (bf16). MODE 1: P = mask? exp(acc*scale):0 (bf16) +
// atomic row sums. MODE 2: C = acc / sumrow[row] (fp32).
template <typename CT, int MODE, int K>
__device__ __forceinline__ void gemm256(
    bf16* lds,
    const bf16* __restrict__ A, const bf16* __restrict__ B, CT* __restrict__ C,
    int lda, int ldb, int ldc, int m0, int n0, float scale,
    const unsigned* __restrict__ mrow, float* __restrict__ sumrow)
{
  const int t = threadIdx.x;            // 0..511
  const int lane = t & 63;
  const int w = t >> 6;                 // 0..7
  const int wm = w >> 2, wn = w & 3;    // 2 x 4
  const int rr = lane & 15, q4 = lane >> 4;

  // Staging thread coords (R7-proven pattern, extended to 512 threads).
  const int s64row = t >> 3;                 // 0..63
  const int ssl    = t & 7;                  // dest slot
  const int s64ch  = ssl ^ (s64row & 7);     // source chunk (64-row stage)
  const int tb     = t & 255;
  const int sbrow  = tb >> 3;                // 0..31
  const int sbch   = ssl ^ (sbrow & 7);      // source chunk (32-row bands)
  const int hb     = t >> 8;                 // which band within a B stage

  constexpr int nT = K >> 6;

  // Hoisted per-thread bases.
  const bf16* Ag = A + (size_t)(m0 + s64row) * lda + s64ch * 8;
  const bf16* Bg = B + (size_t)(n0 + hb * 64 + sbrow) * ldb + sbch * 8;
  bf16* stAd = lds + t * 8;                               // + buf + row0*64
  bf16* stBd = lds + 16384 + (hb * 64 + sbrow) * 64 + ssl * 8;  // + buf + b0*64

  // Stage 64 consecutive A rows [row0,row0+64) of k-tile tt. 1 load/thread.
  auto stageA = [&](int tt, int row0) {
    gload_lds16(Ag + (size_t)row0 * lda + tt * 64,
                stAd + (tt & 1) * 32768 + row0 * 64);
  };
  // Stage B bands [b0,b0+32) and [b0+64,b0+96) of k-tile tt. 1 load/thread.
  auto stageB = [&](int tt, int b0) {
    gload_lds16(Bg + (size_t)b0 * ldb + tt * 64,
                stBd + (tt & 1) * 32768 + b0 * 64);
  };

  // Prologue: full tile 0 in stage order S1,S2,S3,S4; certify S1,S2.
  stageA(0, 0);   stageA(0, 128);   // S1
  stageB(0, 0);   stageB(0, 128);   // S2
  stageB(0, 32);  stageB(0, 160);   // S3
  stageA(0, 64);  stageA(0, 192);   // S4
  asm volatile("s_waitcnt vmcnt(4)" ::: "memory");
  __builtin_amdgcn_s_barrier();
  SBAR0;

  f32x4 acc[8][4] = {};
  bf16x8 af[2][4];   // [kk][m within half]
  bf16x8 bgf[2][4];  // [kk][n], lives across the whole tile

  // Fragment swizzle collapses: R&7 == rr&7 for every fragment row.
  const int sw0 = (q4 ^ (rr & 7)) << 3;  // elem offset, kk=0
  const int sw1 = sw0 ^ 32;              // kk=1

#pragma unroll
  for (int tt = 0; tt < nT; ++tt) {
    const bf16* Ab = lds + (tt & 1) * 32768 + (wm * 128 + rr) * 64;
    const bf16* Bb = lds + (tt & 1) * 32768 + 16384 + (wn * 64 + rr) * 64;
    const bool pf = (tt + 1) < nT;   // compile-time after unroll

    // ---------------- P1: A m0-3, B n0-1; MFMA m0-3 x n0-1 ----------------
#pragma unroll
    for (int m = 0; m < 4; ++m) {
      af[0][m] = *(const bf16x8*)(Ab + m * 1024 + sw0);
      af[1][m] = *(const bf16x8*)(Ab + m * 1024 + sw1);
    }
#pragma unroll
    for (int n = 0; n < 2; ++n) {
      bgf[0][n] = *(const bf16x8*)(Bb + n * 1024 + sw0);
      bgf[1][n] = *(const bf16x8*)(Bb + n * 1024 + sw1);
    }
    if (pf) { stageA(tt + 1, 0); stageA(tt + 1, 128); }   // S1'
    if (pf) asm volatile("s_waitcnt vmcnt(4)" ::: "memory");
    else    asm volatile("s_waitcnt vmcnt(2)" ::: "memory");
    __builtin_amdgcn_s_barrier();
    SBAR0;
    __builtin_amdgcn_s_setprio(1);
#pragma unroll
    for (int kk = 0; kk < 2; ++kk)
#pragma unroll
      for (int m = 0; m < 4; ++m)
#pragma unroll
        for (int n = 0; n < 2; ++n)
          acc[m][n] = __builtin_amdgcn_mfma_f32_16x16x32_bf16(af[kk][m], bgf[kk][n], acc[m][n], 0, 0, 0);
    __builtin_amdgcn_s_setprio(0);

    // ---------------- P2: B n2-3; MFMA m0-3 x n2-3 ----------------
#pragma unroll
    for (int n = 2; n < 4; ++n) {
      bgf[0][n] = *(const bf16x8*)(Bb + n * 1024 + sw0);
      bgf[1][n] = *(const bf16x8*)(Bb + n * 1024 + sw1);
    }
    if (pf) { stageB(tt + 1, 0); stageB(tt + 1, 128); }   // S2'
    if (pf) asm volatile("s_waitcnt vmcnt(4)" ::: "memory");
    else    asm volatile("s_waitcnt vmcnt(0)" ::: "memory");
    __builtin_amdgcn_s_barrier();
    SBAR0;
    __builtin_amdgcn_s_setprio(1);
#pragma unroll
    for (int kk = 0; kk < 2; ++kk)
#pragma unroll
      for (int m = 0; m < 4; ++m)
#pragma unroll
        for (int n = 2; n < 4; ++n)
          acc[m][n] = __builtin_amdgcn_mfma_f32_16x16x32_bf16(af[kk][m], bgf[kk][n], acc[m][n], 0, 0, 0);
    __builtin_amdgcn_s_setprio(0);

    // ---------------- P3: A m4-7; MFMA m4-7 x n0-1 ----------------
#pragma unroll
    for (int m = 0; m < 4; ++m) {
      af[0][m] = *(const bf16x8*)(Ab + (64 + m * 16) * 64 + sw0);
      af[1][m] = *(const bf16x8*)(Ab + (64 + m * 16) * 64 + sw1);
    }
    if (pf) { stageB(tt + 1, 32); stageB(tt + 1, 160); }  // S3'
    __builtin_amdgcn_s_barrier();   // no vmcnt: P3 reads S4(t), certified at P2
    SBAR0;
    __builtin_amdgcn_s_setprio(1);
#pragma unroll
    for (int kk = 0; kk < 2; ++kk)
#pragma unroll
      for (int m = 0; m < 4; ++m)
#pragma unroll
        for (int n = 0; n < 2; ++n)
          acc[4 + m][n] = __builtin_amdgcn_mfma_f32_16x16x32_bf16(af[kk][m], bgf[kk][n], acc[4 + m][n], 0, 0, 0);
    __builtin_amdgcn_s_setprio(0);

    // ---------------- P4: MFMA m4-7 x n2-3 ----------------
    if (pf) { stageA(tt + 1, 64); stageA(tt + 1, 192); }  // S4'
    if (pf) asm volatile("s_waitcnt vmcnt(4)" ::: "memory");
    __builtin_amdgcn_s_barrier();
    SBAR0;
    __builtin_amdgcn_s_setprio(1);
#pragma unroll
    for (int kk = 0; kk < 2; ++kk)
#pragma unroll
      for (int m = 0; m < 4; ++m)
#pragma unroll
        for (int n = 2; n < 4; ++n)
          acc[4 + m][n] = __builtin_amdgcn_mfma_f32_16x16x32_bf16(af[kk][m], bgf[kk][n], acc[4 + m][n], 0, 0, 0);
    __builtin_amdgcn_s_setprio(0);
  }

  // C/D frag: col = lane&15, row = (lane>>4)*4 + reg  (R7/R8/R9-verified)
  if (MODE == 0) {
#pragma unroll
    for (int m = 0; m < 8; ++m) {
#pragma unroll
      for (int n = 0; n < 4; ++n) {
        const int gr0 = m0 + wm * 128 + m * 16 + (q4 << 2);
        const int gc = n0 + wn * 64 + n * 16 + rr;
#pragma unroll
        for (int i = 0; i < 4; ++i)
          C[(size_t)(gr0 + i) * ldc + gc] = (CT)(acc[m][n][i] * scale);
      }
    }
  } else if (MODE == 1) {
    const int cb0 = (n0 + wn * 64) >> 5;
#pragma unroll
    for (int m = 0; m < 8; ++m) {
#pragma unroll
      for (int i = 0; i < 4; ++i) {
        const int row = m0 + wm * 128 + m * 16 + (q4 << 2) + i;
        const unsigned mw0 = mrow[(row << 5) + cb0];
        const unsigned mw1 = mrow[(row << 5) + cb0 + 1];
        float ps = 0.0f;
#pragma unroll
        for (int n = 0; n < 4; ++n) {
          const int gc = n0 + wn * 64 + n * 16 + rr;
          const unsigned mw = (n >= 2) ? mw1 : mw0;
          const unsigned bit = (mw >> (((n & 1) << 4) + rr)) & 1u;
          float p = bit ? __expf(acc[m][n][i] * scale) : 0.0f;
          C[(size_t)row * ldc + gc] = (CT)p;
          ps += p;
        }
        ps += __shfl_xor(ps, 1); ps += __shfl_xor(ps, 2);
        ps += __shfl_xor(ps, 4); ps += __shfl_xor(ps, 8);
        if (rr == 0) atomicAdd(sumrow + row, ps);
      }
    }
  } else {
#pragma unroll
    for (int m = 0; m < 8; ++m) {
      const int gr0 = m0 + wm * 128 + m * 16 + (q4 << 2);
      float inv[4];
#pragma unroll
      for (int i = 0; i < 4; ++i) inv[i] = 1.0f / sumrow[gr0 + i];
#pragma unroll
      for (int n = 0; n < 4; ++n) {
        const int gc = n0 + wn * 64 + n * 16 + rr;
#pragma unroll
        for (int i = 0; i < 4; ++i)
          C[(size_t)(gr0 + i) * ldc + gc] = (CT)(acc[m][n][i] * inv[i]);
      }
    }
  }
}

// ---- Dispatch 1: prep (cvt5 + cvtT + pack_mask + zero sums). grid 12832. ----
__global__ __launch_bounds__(256) void prep_kernel(
    const float* __restrict__ x, const float* __restrict__ st,
    const float* __restrict__ Wq, const float* __restrict__ Wk,
    const float* __restrict__ Wp, const float* __restrict__ Wv,
    const int* __restrict__ mask,
    bf16* __restrict__ xb, bf16* __restrict__ stb, bf16* __restrict__ wqb,
    bf16* __restrict__ wkb, bf16* __restrict__ wpb, bf16* __restrict__ WvT,
    unsigned* __restrict__ mbits, float* __restrict__ sums)
{
  const int lin = blockIdx.x;
  const int t = threadIdx.x;
  if (lin < 10240) {
    const float* s; bf16* d;
    switch (lin >> 11) {
      case 0: s = x; d = xb; break;
      case 1: s = st; d = stb; break;
      case 2: s = Wq; d = wqb; break;
      case 3: s = Wk; d = wkb; break;
      default: s = Wp; d = wpb; break;
    }
    const int i = ((lin & 2047) * 256 + t) * 4;
    float4 v = *(const float4*)(s + i);
    bf16x4 o;
    o[0] = (bf16)v.x; o[1] = (bf16)v.y; o[2] = (bf16)v.z; o[3] = (bf16)v.w;
    *(bf16x4*)(d + i) = o;
  } else if (lin < 12288) {
    // WvT[h][d][e'] = Wv[h][e'][d]
    const int gid = (lin - 10240) * 256 + t;      // [0, 524288)
    const int e0 = (gid & 127) * 4;
    const int d = (gid >> 7) & 511;
    const int h = gid >> 16;
    const float* src = Wv + (size_t)h * 262144 + (size_t)e0 * 512 + d;
    bf16x4 o;
    o[0] = (bf16)src[0];
    o[1] = (bf16)src[512];
    o[2] = (bf16)src[1024];
    o[3] = (bf16)src[1536];
    *(bf16x4*)(WvT + (size_t)h * 262144 + (size_t)d * 512 + e0) = o;
  } else if (lin < 12800) {
    const int gid = (lin - 12288) * 256 + t;      // [0, 131072)
    const int* src = mask + (size_t)gid * 32;
    unsigned bits = 0;
#pragma unroll
    for (int j = 0; j < 32; j += 4) {
      int4 v = *(const int4*)(src + j);
      if (v.x) bits |= 1u << j;
      if (v.y) bits |= 1u << (j + 1);
      if (v.z) bits |= 1u << (j + 2);
      if (v.w) bits |= 1u << (j + 3);
    }
    mbits[gid] = bits;
  } else {
    const int i = ((lin - 12800) * 256 + t) * 4;  // [0, 32768) floats
    *(float4*)(sums + i) = make_float4(0.f, 0.f, 0.f, 0.f);
  }
}

// ---- Dispatch 2: proj (q/k projections + U = Wp_h.Wv_h). grid 544x512. ----
__global__ __launch_bounds__(512, 2) void proj_kernel(
    const bf16* __restrict__ xb, const bf16* __restrict__ stb,
    const bf16* __restrict__ wqb, const bf16* __restrict__ wkb,
    const bf16* __restrict__ wpb, const bf16* __restrict__ WvT,
    bf16* __restrict__ q, bf16* __restrict__ k, bf16* __restrict__ U)
{
  __shared__ bf16 lds[65536];   // 128 KB
  const int bid = blockIdx.x;
  const int g = (bid & 7) * 68 + (bid >> 3);   // XCD-chunked, 544 = 8*68
  if (g < 512) {
    const int z = g >> 3;        // 0..63 : job*32 + (zb*8+zh)
    const int tile = g & 7;      // 4 m x 2 n
    const int job = z >> 5;
    const int zz = z & 31;
    const size_t zb = zz >> 3, zh = zz & 7;
    const bf16* Ain = job ? stb : xb;
    const bf16* W = job ? wkb : wqb;
    bf16* Cout = job ? k : q;
    gemm256<bf16, 0, 512>(lds, Ain + zb * 524288, W + zh * 262144,
        Cout + zb * 4194304 + zh * 524288, 512, 512, 512,
        (tile >> 1) * 256, (tile & 1) * 256, 1.0f, nullptr, nullptr);
  } else {
    // U_h[e,d] = sum_e' Wp[e, h*512+e'] * WvT_h[d, e']
    const int g2 = g - 512;      // 0..31
    const int h = g2 >> 2;
    const int tile = g2 & 3;     // 2 m x 2 n
    gemm256<bf16, 0, 512>(lds, wpb + (size_t)h * 512, WvT + (size_t)h * 262144,
        U + (size_t)h * 262144, 4096, 512, 512,
        (tile >> 1) * 256, (tile & 1) * 256, 1.0f, nullptr, nullptr);
  }
}

// ---- Dispatch 3: big (scores+exp+rowsum, and VWT = U.states^T). grid 768x512. ----
__global__ __launch_bounds__(512, 2) void big_kernel(
    const bf16* __restrict__ q, const bf16* __restrict__ k,
    const bf16* __restrict__ U, const bf16* __restrict__ stb,
    bf16* __restrict__ P, bf16* __restrict__ VWT,
    const unsigned* __restrict__ mbits, float* __restrict__ sums, float scale)
{
  __shared__ bf16 lds[65536];
  const int bid = blockIdx.x;
  const int g = (bid & 7) * 96 + (bid >> 3);   // 768 = 8*96
  if (g < 512) {
    // scores: z in [0,32), 16 tiles (4m x 4n)
    const int z = g >> 4;
    const int tile = g & 15;
    const size_t zb = z >> 3, zh = z & 7;
    gemm256<bf16, 1, 512>(lds,
        q + zb * 4194304 + zh * 524288,
        k + zb * 4194304 + zh * 524288,
        P + zb * 8388608 + zh * 1048576,
        512, 512, 1024,
        (tile >> 2) * 256, (tile & 3) * 256, scale,
        mbits + (zb << 15), sums + ((size_t)z << 10));
  } else {
    // VWT[b,h][e,s] = U_h . states_b^T : z in [0,32), 8 tiles (2m x 4n)
    const int g2 = g - 512;
    const int z = g2 >> 3;
    const int tile = g2 & 7;
    const size_t zb = z >> 3, zh = z & 7;
    gemm256<bf16, 0, 512>(lds, U + zh * 262144, stb + zb * 524288,
        VWT + zb * 4194304 + zh * 524288, 512, 512, 1024,
        (tile >> 2) * 256, (tile & 3) * 256, 1.0f, nullptr, nullptr);
  }
}

// ---- Dispatch 4: pvw — part[h] = (1/sum_h) ⊙ (P_h·VWT_h^T). grid 256x512. ----
__global__ __launch_bounds__(512, 2) void pvw_kernel(
    const bf16* __restrict__ P, const bf16* __restrict__ VWT,
    float* __restrict__ sums, float* __restrict__ part)
{
  __shared__ bf16 lds[65536];
  const int bid = blockIdx.x;
  const int g = (bid & 7) * 32 + (bid >> 3);   // 256 = 8*32
  const int z = g >> 3;        // 0..31 = (b,h)
  const int tile = g & 7;      // 4 m(l) x 2 n(e)
  const size_t zb = z >> 3, zh = z & 7;
  gemm256<float, 2, 1024>(lds,
      P + zb * 8388608 + zh * 1048576,
      VWT + zb * 4194304 + zh * 524288,
      part + zh * 2097152 + zb * 524288,
      1024, 1024, 512,
      (tile >> 1) * 256, (tile & 1) * 256, 1.0f,
      nullptr, sums + ((size_t)z << 10));
}

// ---- Dispatch 5: out = sum of 8 per-head parts. grid 2048x256. ----
__global__ __launch_bounds__(256) void reduce8(
    const float* __restrict__ part, float* __restrict__ out)
{
  const size_t i = ((size_t)blockIdx.x * 256 + threadIdx.x) * 4;
  float4 o = *(const float4*)(part + i);
#pragma unroll
  for (int h = 1; h < 8; ++h) {
    float4 a = *(const float4*)(part + (size_t)h * 2097152 + i);
    o.x += a.x; o.y += a.y; o.z += a.z; o.w += a.w;
  }
  *(float4*)(out + i) = o;
}

extern "C" void kernel_launch(void* const* d_in, const int* in_sizes, int n_in,
                              void* d_out, int out_size, void* d_ws, size_t ws_size,
                              hipStream_t stream) {
  const float* x    = (const float*)d_in[0];
  const float* st   = (const float*)d_in[1];
  const int*   mask = (const int*)d_in[2];
  const float* Wq   = (const float*)d_in[3];
  const float* Wk   = (const float*)d_in[4];
  const float* Wv   = (const float*)d_in[5];
  const float* Wp   = (const float*)d_in[6];
  float* out = (float*)d_out;

  char* ws = (char*)d_ws;
  const size_t MB = 1048576;
  bf16* xb  = (bf16*)(ws);               // 4MB
  bf16* stb = (bf16*)(ws + 4 * MB);      // 4MB (live through VWT)
  bf16* wqb = (bf16*)(ws + 8 * MB);      // 4MB
  bf16* wkb = (bf16*)(ws + 12 * MB);     // 4MB
  bf16* wpb = (bf16*)(ws + 16 * MB);     // 4MB
  bf16* WvT = (bf16*)(ws + 20 * MB);     // 4MB [8,512,512] transposed
  bf16* U   = (bf16*)(ws + 24 * MB);     // 4MB [8,512,512] Wp_h.Wv_h
  bf16* q   = (bf16*)(ws + 28 * MB);     // 32MB; dead after scores
  bf16* k   = (bf16*)(ws + 60 * MB);     // 32MB; dead after scores
  bf16* VWT = (bf16*)(ws + 92 * MB);     // 32MB [4,8,512,1024]
  bf16* sc  = (bf16*)(ws + 124 * MB);    // 64MB P = exp(scores)
  unsigned* mbits = (unsigned*)(ws + 188 * MB);  // 512KB
  float*    sums  = (float*)(ws + 189 * MB);     // 128KB
  float*    part  = (float*)(ws + 28 * MB);      // 64MB fp32 (over q+k)

  const float scale = 0.04419417382415922f;  // 1/sqrt(512)

  prep_kernel<<<dim3(12832), dim3(256), 0, stream>>>(x, st, Wq, Wk, Wp, Wv, mask,
      xb, stb, wqb, wkb, wpb, WvT, mbits, sums);

  proj_kernel<<<dim3(544), dim3(512), 0, stream>>>(xb, stb, wqb, wkb, wpb, WvT,
      q, k, U);

  big_kernel<<<dim3(768), dim3(512), 0, stream>>>(q, k, U, stb, sc, VWT,
      mbits, sums, scale);

  pvw_kernel<<<dim3(256), dim3(512), 0, stream>>>(sc, VWT, sums, part);

  reduce8<<<dim3(2048), dim3(256), 0, stream>>>(part, out);
}